// Round 14
// baseline (392.142 us; speedup 1.0000x reference)
//
#include <hip/hip_runtime.h>
#include <hip/hip_bf16.h>
#include <math.h>

#define Bdim 2
#define Sdim 4096
#define Hdim 1024
#define Edim 8
#define Ddim 2048
#define Tdim (Bdim*Sdim)   // 8192 tokens

typedef __attribute__((ext_vector_type(8))) __bf16 bfv8;
typedef __attribute__((ext_vector_type(8))) short s16x8;
typedef __attribute__((ext_vector_type(4))) short s16x4;
typedef __attribute__((ext_vector_type(4))) float f32x4;

__device__ __forceinline__ short f2bf(float f) {
    union { float f; unsigned u; } a; a.f = f;
    unsigned r = (a.u + 0x7fffu + ((a.u >> 16) & 1u)) >> 16;
    return (short)r;
}
__device__ __forceinline__ float bf2f(short s) {
    union { unsigned u; float f; } a; a.u = ((unsigned)(unsigned short)s) << 16;
    return a.f;
}
// tanh-form gelu via exp; |err| < 1e-3 abs (below bf16 GEMM noise)
__device__ __forceinline__ float fgelu(float x) {
    float u = fminf(x * (1.5957691f + 0.07135481f * x * x), 60.0f);
    float t = __expf(u);
    return x * t / (t + 1.0f);
}

typedef const __attribute__((address_space(1))) unsigned int ga_u32;
typedef __attribute__((address_space(3))) unsigned int la_u32;

__device__ __forceinline__ void gl_lds16(const void* g, void* l) {
    __builtin_amdgcn_global_load_lds((ga_u32*)g, (la_u32*)l, 16, 0, 0);
}

#define SYNC0() do {                                                     \
    asm volatile("s_waitcnt vmcnt(0)" ::: "memory");                     \
    __builtin_amdgcn_s_barrier();                                        \
    __builtin_amdgcn_sched_barrier(0);                                   \
} while (0)

// ---- gemm1 (256x256, af[8] bf[4], 32 MFMA/phase) ----
#define RD1(S) do {                                                                  \
    _Pragma("unroll") for (int n = 0; n < 4; ++n)                                    \
        bf[n] = *(const bfv8*)(lds + 16384 + (S) * 8192 + offB[n]);                  \
    _Pragma("unroll") for (int m = 0; m < 8; ++m)                                    \
        af[m] = *(const bfv8*)(lds + (S) * 8192 + offA[m]);                          \
    __builtin_amdgcn_sched_barrier(0);                                               \
} while (0)
#define MM1() do {                                                                   \
    __builtin_amdgcn_s_setprio(1);                                                   \
    _Pragma("unroll") for (int m = 0; m < 8; ++m)                                    \
        _Pragma("unroll") for (int n = 0; n < 4; ++n)                                \
            acc[m][n] = __builtin_amdgcn_mfma_f32_16x16x32_bf16(af[m], bf[n], acc[m][n], 0, 0, 0); \
    __builtin_amdgcn_s_setprio(0);                                                   \
    __builtin_amdgcn_sched_barrier(0);                                               \
} while (0)
#define PH1F(SST, SRD) do { stage(SST); RD1(SRD); MM1(); SYNC0(); } while (0)
#define PH1L(SRD)      do { RD1(SRD); MM1(); } while (0)

// ---- gemm2 (256x128, af[4] bf[4], 16 MFMA/phase) ----
#define RD2(S) do {                                                                  \
    _Pragma("unroll") for (int n = 0; n < 4; ++n)                                    \
        bf[n] = *(const bfv8*)(lds + 16384 + (S) * 4096 + offB[n]);                  \
    _Pragma("unroll") for (int m = 0; m < 4; ++m)                                    \
        af[m] = *(const bfv8*)(lds + (S) * 8192 + offA[m]);                          \
    __builtin_amdgcn_sched_barrier(0);                                               \
} while (0)
#define MM2() do {                                                                   \
    __builtin_amdgcn_s_setprio(1);                                                   \
    _Pragma("unroll") for (int m = 0; m < 4; ++m)                                    \
        _Pragma("unroll") for (int n = 0; n < 4; ++n)                                \
            acc[m][n] = __builtin_amdgcn_mfma_f32_16x16x32_bf16(af[m], bf[n], acc[m][n], 0, 0, 0); \
    __builtin_amdgcn_s_setprio(0);                                                   \
    __builtin_amdgcn_sched_barrier(0);                                               \
} while (0)
#define PH2F(SST, SRD) do { stage(SST); RD2(SRD); MM2(); SYNC0(); } while (0)
#define PH2L(SRD)      do { RD2(SRD); MM2(); } while (0)

// ---------------- Fused prep: router (blocks 0..511) + weight convert (512..8703) ----------------
union PrepSm {
    struct {
        float gws[Edim * Hdim];
        int lcnt[8], gbase[8];
        int s_e[32], s_pos[32], s_tok[32];
        float s_w[32];
        float s_ps[4][8];
    } r;
    struct { short t[64][76]; } c;
};

__global__ __launch_bounds__(256) void prep_kernel(
    const float* __restrict__ x, const float* __restrict__ gw,
    const float* __restrict__ w1, const float* __restrict__ w2,
    int* __restrict__ cnt, float* __restrict__ psum,
    int* __restrict__ ltok, float* __restrict__ lw,
    short* __restrict__ xb, short* __restrict__ w1t, short* __restrict__ w2t)
{
    __shared__ PrepSm sm;
    int tid = threadIdx.x;

    if (blockIdx.x < Tdim / 16) {
        // ======== router: 512 blocks, wave handles 4 tokens; also emits xb ========
        int bid = blockIdx.x;
        for (int i = tid; i < Edim * Hdim / 4; i += 256)
            ((float4*)sm.r.gws)[i] = ((const float4*)gw)[i];
        if (tid < Edim) sm.r.lcnt[tid] = 0;
        __syncthreads();

        int wave = tid >> 6, lane = tid & 63;
        float ps = 0.f;

        for (int i = 0; i < 4; ++i) {
            int t = bid * 16 + wave * 4 + i;
            double acc[Edim];
#pragma unroll
            for (int e = 0; e < Edim; ++e) acc[e] = 0.0;
#pragma unroll
            for (int kq = 0; kq < 4; ++kq) {
                float4 xv = *(const float4*)(x + (size_t)t * Hdim + kq * 256 + lane * 4);
                s16x4 h; h[0]=f2bf(xv.x); h[1]=f2bf(xv.y); h[2]=f2bf(xv.z); h[3]=f2bf(xv.w);
                *(s16x4*)(xb + (size_t)t * Hdim + kq * 256 + lane * 4) = h;
#pragma unroll
                for (int e = 0; e < Edim; ++e) {
                    float4 wv = *(const float4*)(&sm.r.gws[e * Hdim + kq * 256 + lane * 4]);
                    acc[e] += (double)xv.x * wv.x + (double)xv.y * wv.y
                            + (double)xv.z * wv.z + (double)xv.w * wv.w;
                }
            }
#pragma unroll
            for (int e = 0; e < Edim; ++e) {
                acc[e] += __shfl_xor(acc[e], 1, 64);
                acc[e] += __shfl_xor(acc[e], 2, 64);
                acc[e] += __shfl_xor(acc[e], 4, 64);
            }
            int el = lane & 7;
            double v = acc[0];
#pragma unroll
            for (int e = 1; e < Edim; ++e) if (el == e) v = acc[e];
            v += __shfl_xor(v, 8, 64);
            v += __shfl_xor(v, 16, 64);
            v += __shfl_xor(v, 32, 64);
            double mx = v;
            mx = fmax(mx, __shfl_xor(mx, 1, 64));
            mx = fmax(mx, __shfl_xor(mx, 2, 64));
            mx = fmax(mx, __shfl_xor(mx, 4, 64));
            float ex = __expf((float)(v - mx));
            float smv = ex;
            smv += __shfl_xor(smv, 1, 64);
            smv += __shfl_xor(smv, 2, 64);
            smv += __shfl_xor(smv, 4, 64);
            ps += ex / smv;
            double le[8];
#pragma unroll
            for (int e = 0; e < 8; ++e) le[e] = __shfl(v, e, 8);
            if (lane == 0) {
                int e1 = 0;
#pragma unroll
                for (int e = 1; e < 8; ++e) if (le[e] > le[e1]) e1 = e;
                int e2 = -1;
#pragma unroll
                for (int e = 0; e < 8; ++e) {
                    if (e == e1) continue;
                    if (e2 < 0 || le[e] > le[e2]) e2 = e;
                }
                float r = __expf((float)(le[e2] - le[e1]));   // p2/p1
                float w1v = 1.0f / (1.0f + r);
                int lt = (wave * 4 + i) * 2;
                int p1 = atomicAdd(&sm.r.lcnt[e1], 1);
                sm.r.s_e[lt] = e1; sm.r.s_pos[lt] = p1; sm.r.s_tok[lt] = 2*t;     sm.r.s_w[lt] = w1v;
                int p2 = atomicAdd(&sm.r.lcnt[e2], 1);
                sm.r.s_e[lt+1] = e2; sm.r.s_pos[lt+1] = p2; sm.r.s_tok[lt+1] = 2*t+1; sm.r.s_w[lt+1] = 1.0f - w1v;
            }
        }
        if (lane < 8) sm.r.s_ps[wave][lane] = ps;
        __syncthreads();
        if (tid < 8) {
            atomicAdd(&psum[tid], sm.r.s_ps[0][tid] + sm.r.s_ps[1][tid] + sm.r.s_ps[2][tid] + sm.r.s_ps[3][tid]);
            sm.r.gbase[tid] = atomicAdd(&cnt[tid], sm.r.lcnt[tid]);
        }
        __syncthreads();
        if (tid < 32) {
            int e = sm.r.s_e[tid];
            int pos = sm.r.gbase[e] + sm.r.s_pos[tid];
            ltok[e * Tdim + pos] = sm.r.s_tok[tid];
            lw[e * Tdim + pos] = sm.r.s_w[tid];
        }
    } else {
        // ======== weight transpose-convert: 8192 blocks ========
        int id = blockIdx.x - Tdim / 16;
        int bz = id >> 9, by = (id >> 5) & 15, bx = id & 31;
        const float* w; short* wt; int R, C, r0, c0, e;
        if (bz < 8) { e = bz;     w = w1; wt = w1t; R = Hdim; C = Ddim; r0 = by * 64; c0 = bx * 64; }
        else        { e = bz - 8; w = w2; wt = w2t; R = Ddim; C = Hdim; r0 = bx * 64; c0 = by * 64; }

        {
            int r = tid >> 2, cs = (tid & 3) * 16;
            const float* src = w + ((size_t)e * R + r0 + r) * C + c0 + cs;
#pragma unroll
            for (int q = 0; q < 4; ++q) {
                float4 v = *(const float4*)(src + q * 4);
                s16x4 h; h[0]=f2bf(v.x); h[1]=f2bf(v.y); h[2]=f2bf(v.z); h[3]=f2bf(v.w);
                *(s16x4*)(&sm.c.t[r][cs + q * 4]) = h;
            }
        }
        __syncthreads();
        {
            int c = tid >> 2, rs = (tid & 3) * 16;
            short tmp[16];
#pragma unroll
            for (int j = 0; j < 16; ++j) tmp[j] = sm.c.t[rs + j][c];
            short* dst = wt + ((size_t)e * C + c0 + c) * R + r0 + rs;
            *(s16x8*)dst = *(s16x8*)tmp;
            *(s16x8*)(dst + 8) = *(s16x8*)(tmp + 8);
        }
    }
}

// ---------------- Aux loss + prefix offsets ----------------
__global__ void aux_kernel(const int* __restrict__ cnt,
                           const float* __restrict__ psum,
                           int* __restrict__ eoff,
                           float* __restrict__ out_aux)
{
    if (threadIdx.x == 0 && blockIdx.x == 0) {
        double s = 0.0;
        int run = 0;
        for (int e = 0; e < Edim; ++e) {
            eoff[e] = run;
            run += cnt[e];
            s += ((double)cnt[e] / (double)Bdim) * ((double)psum[e] / (double)Tdim);
        }
        out_aux[0] = (float)((double)Edim * s);
    }
}

// ---------------- Router (fallback path only) ----------------
__global__ __launch_bounds__(256) void router_kernel(
    const float* __restrict__ x, const float* __restrict__ gw,
    int* __restrict__ cnt, float* __restrict__ psum,
    int* __restrict__ ltok, float* __restrict__ lw)
{
    __shared__ float gws[Edim * Hdim];
    __shared__ int   lcnt[Edim], gbase[Edim];
    __shared__ int   s_e[32], s_pos[32], s_tok[32];
    __shared__ float s_w[32];
    __shared__ float s_ps[4][8];

    int tid = threadIdx.x;
    for (int i = tid; i < Edim * Hdim / 4; i += 256)
        ((float4*)gws)[i] = ((const float4*)gw)[i];
    if (tid < Edim) lcnt[tid] = 0;
    __syncthreads();

    int wave = tid >> 6, lane = tid & 63;
    float ps = 0.f;

    for (int i = 0; i < 4; ++i) {
        int t = blockIdx.x * 16 + wave * 4 + i;
        double acc[Edim];
#pragma unroll
        for (int e = 0; e < Edim; ++e) acc[e] = 0.0;
#pragma unroll
        for (int kq = 0; kq < 4; ++kq) {
            float4 xv = *(const float4*)(x + (size_t)t * Hdim + kq * 256 + lane * 4);
#pragma unroll
            for (int e = 0; e < Edim; ++e) {
                float4 wv = *(const float4*)(&gws[e * Hdim + kq * 256 + lane * 4]);
                acc[e] += (double)xv.x * wv.x + (double)xv.y * wv.y
                        + (double)xv.z * wv.z + (double)xv.w * wv.w;
            }
        }
#pragma unroll
        for (int e = 0; e < Edim; ++e) {
            acc[e] += __shfl_xor(acc[e], 1, 64);
            acc[e] += __shfl_xor(acc[e], 2, 64);
            acc[e] += __shfl_xor(acc[e], 4, 64);
        }
        int el = lane & 7;
        double v = acc[0];
#pragma unroll
        for (int e = 1; e < Edim; ++e) if (el == e) v = acc[e];
        v += __shfl_xor(v, 8, 64);
        v += __shfl_xor(v, 16, 64);
        v += __shfl_xor(v, 32, 64);
        double mx = v;
        mx = fmax(mx, __shfl_xor(mx, 1, 64));
        mx = fmax(mx, __shfl_xor(mx, 2, 64));
        mx = fmax(mx, __shfl_xor(mx, 4, 64));
        float ex = __expf((float)(v - mx));
        float smv = ex;
        smv += __shfl_xor(smv, 1, 64);
        smv += __shfl_xor(smv, 2, 64);
        smv += __shfl_xor(smv, 4, 64);
        ps += ex / smv;
        double le[8];
#pragma unroll
        for (int e = 0; e < 8; ++e) le[e] = __shfl(v, e, 8);
        if (lane == 0) {
            int e1 = 0;
#pragma unroll
            for (int e = 1; e < 8; ++e) if (le[e] > le[e1]) e1 = e;
            int e2 = -1;
#pragma unroll
            for (int e = 0; e < 8; ++e) {
                if (e == e1) continue;
                if (e2 < 0 || le[e] > le[e2]) e2 = e;
            }
            float r = __expf((float)(le[e2] - le[e1]));
            float w1v = 1.0f / (1.0f + r);
            int lt = (wave * 4 + i) * 2;
            int p1 = atomicAdd(&lcnt[e1], 1);
            s_e[lt] = e1; s_pos[lt] = p1; s_tok[lt] = 2*t;     s_w[lt] = w1v;
            int p2 = atomicAdd(&lcnt[e2], 1);
            s_e[lt+1] = e2; s_pos[lt+1] = p2; s_tok[lt+1] = 2*t+1; s_w[lt+1] = 1.0f - w1v;
        }
    }
    if (lane < 8) s_ps[wave][lane] = ps;
    __syncthreads();
    if (tid < 8) {
        atomicAdd(&psum[tid], s_ps[0][tid] + s_ps[1][tid] + s_ps[2][tid] + s_ps[3][tid]);
        gbase[tid] = atomicAdd(&cnt[tid], lcnt[tid]);
    }
    __syncthreads();
    if (tid < 32) {
        int e = s_e[tid];
        int pos = gbase[e] + s_pos[tid];
        ltok[e * Tdim + pos] = s_tok[tid];
        lw[e * Tdim + pos] = s_w[tid];
    }
}

// ====== GEMM1: 256x256, 8 waves (wave-tile 128x64), BK=32, 2 slots, 64KB LDS ======
__global__ __launch_bounds__(512, 2) void gemm1n_kernel(
    const short* __restrict__ xb, const short* __restrict__ w1t,
    const float* __restrict__ b1, const int* __restrict__ cnt,
    const int* __restrict__ eoff, const int* __restrict__ ltok,
    short* __restrict__ hid)
{
    constexpr int GXN = Ddim / 256;  // 8
    int id = blockIdx.x;
    int e = id & 7;                  // expert == XCD
    unsigned rem = (unsigned)id >> 3;
    int bx = rem & (GXN - 1);
    int by = rem / GXN;

    int n_e = cnt[e];
    int row0 = by * 256;
    if (row0 >= n_e) return;
    int col0 = bx * 256;
    int slot0 = eoff[e];

    __shared__ short lds[32768];     // 64 KB
    char* ldsb = (char*)lds;

    int tid = threadIdx.x;
    int w = tid >> 6, lane = tid & 63;

    const short* aS[2]; const short* bS[2];
    int oD[2];
#pragma unroll
    for (int j = 0; j < 2; ++j) {
        int o = tid * 16 + j * 8192;               // dest byte offset within 16KB region
        oD[j] = o;
        int eff = o ^ (((o >> 7) & 7) << 4);       // inverse swizzle
        int row = ((eff >> 7) << 1) | ((eff >> 6) & 1);
        int kB  = eff & 63;
        int gr = row0 + row; if (gr > n_e - 1) gr = n_e - 1;
        int tok = ltok[(size_t)e * Tdim + gr] >> 1;
        aS[j] = xb + (size_t)tok * Hdim + (kB >> 1);
        bS[j] = w1t + ((size_t)e * Ddim + col0 + row) * Hdim + (kB >> 1);
    }

    int fr = lane & 15, kg = lane >> 4;
    int wm = (w >> 2) * 128, wn = (w & 3) * 64;

    int offA[8], offB[4];
#pragma unroll
    for (int m = 0; m < 8; ++m) {
        int r = wm + m * 16 + fr;
        offA[m] = (r >> 1) * 64 + ((((r & 1) * 32) + kg * 8) ^ (((r >> 1) & 7) << 3));
    }
#pragma unroll
    for (int n = 0; n < 4; ++n) {
        int r = wn + n * 16 + fr;
        offB[n] = (r >> 1) * 64 + ((((r & 1) * 32) + kg * 8) ^ (((r >> 1) & 7) << 3));
    }

    f32x4 acc[8][4];
#pragma unroll
    for (int m = 0; m < 8; ++m)
#pragma unroll
        for (int n = 0; n < 4; ++n) acc[m][n] = (f32x4)0.0f;

    bfv8 af[8], bf[4];

    auto stage = [&](int s) {    // 4 gl_lds; advances K by 32 shorts
#pragma unroll
        for (int j = 0; j < 2; ++j) {
            gl_lds16(aS[j], ldsb + s * 16384 + oD[j]);
            aS[j] += 32;
            gl_lds16(bS[j], ldsb + 32768 + s * 16384 + oD[j]);
            bS[j] += 32;
        }
    };

    constexpr int NH = Hdim / 32;    // 32 phases
    stage(0);
    SYNC0();
#pragma unroll 1
    for (int it = 0; it < (NH - 2) / 2; ++it) {
        PH1F(1, 0);
        PH1F(0, 1);
    }
    PH1F(1, 0);
    PH1L(1);

#pragma unroll
    for (int m = 0; m < 8; ++m) {
        int r0r = wm + m * 16 + kg * 4;
#pragma unroll
        for (int j = 0; j < 4; ++j) {
            int gr = row0 + r0r + j;
            if (gr >= n_e) continue;
            size_t hbase = (size_t)(slot0 + gr) * Ddim;
#pragma unroll
            for (int n = 0; n < 4; ++n) {
                int col = col0 + wn + n * 16 + fr;
                float v = acc[m][n][j] + b1[e * Ddim + col];
                hid[hbase + col] = f2bf(fgelu(v));
            }
        }
    }
}

// ====== GEMM2: 256x128, 8 waves (wave-tile 64x64), BK=32, 2 slots, 48KB LDS ======
// epilogue: atomicAdd fp32 directly into out (combine fused; out pre-zeroed)
__global__ __launch_bounds__(512, 2) void gemm2n_kernel(
    const short* __restrict__ hid, const short* __restrict__ w2t,
    const float* __restrict__ b2, const int* __restrict__ cnt,
    const int* __restrict__ eoff, const int* __restrict__ ltok,
    const float* __restrict__ lw, float* __restrict__ out)
{
    constexpr int GXN = Hdim / 128;  // 8
    int id = blockIdx.x;
    int e = id & 7;
    unsigned rem = (unsigned)id >> 3;
    int bx = rem & (GXN - 1);
    int by = rem / GXN;

    int n_e = cnt[e];
    int row0 = by * 256;
    if (row0 >= n_e) return;
    int col0 = bx * 128;
    int slot0 = eoff[e];

    __shared__ short lds[24576];     // 48 KB: A 2x16KB, B 2x8KB
    char* ldsb = (char*)lds;

    int tid = threadIdx.x;
    int w = tid >> 6, lane = tid & 63;

    const short* aS[2]; const short* bS0;
    int oD[2], oB;
#pragma unroll
    for (int j = 0; j < 2; ++j) {
        int o = tid * 16 + j * 8192;
        oD[j] = o;
        int eff = o ^ (((o >> 7) & 7) << 4);
        int row = ((eff >> 7) << 1) | ((eff >> 6) & 1);
        int kB  = eff & 63;
        int gr = row0 + row; if (gr > n_e - 1) gr = n_e - 1;
        aS[j] = hid + (size_t)(slot0 + gr) * Ddim + (kB >> 1);
    }
    {
        int o = tid * 16;
        oB = o;
        int eff = o ^ (((o >> 7) & 7) << 4);
        int row = ((eff >> 7) << 1) | ((eff >> 6) & 1);   // 0..127
        int kB  = eff & 63;
        bS0 = w2t + ((size_t)e * Hdim + col0 + row) * Ddim + (kB >> 1);
    }

    int fr = lane & 15, kg = lane >> 4;
    int wm = (w >> 1) * 64, wn = (w & 1) * 64;

    int offA[4], offB[4];
#pragma unroll
    for (int m = 0; m < 4; ++m) {
        int r = wm + m * 16 + fr;
        offA[m] = (r >> 1) * 64 + ((((r & 1) * 32) + kg * 8) ^ (((r >> 1) & 7) << 3));
    }
#pragma unroll
    for (int n = 0; n < 4; ++n) {
        int r = wn + n * 16 + fr;
        offB[n] = (r >> 1) * 64 + ((((r & 1) * 32) + kg * 8) ^ (((r >> 1) & 7) << 3));
    }

    f32x4 acc[4][4];
#pragma unroll
    for (int m = 0; m < 4; ++m)
#pragma unroll
        for (int n = 0; n < 4; ++n) acc[m][n] = (f32x4)0.0f;

    bfv8 af[4], bf[4];

    auto stage = [&](int s) {    // 3 gl_lds; advances K by 32 shorts
#pragma unroll
        for (int j = 0; j < 2; ++j) {
            gl_lds16(aS[j], ldsb + s * 16384 + oD[j]);
            aS[j] += 32;
        }
        gl_lds16(bS0, ldsb + 32768 + s * 8192 + oB);
        bS0 += 32;
    };

    constexpr int NH = Ddim / 32;    // 64 phases
    stage(0);
    SYNC0();
#pragma unroll 1
    for (int it = 0; it < (NH - 2) / 2; ++it) {
        PH2F(1, 0);
        PH2F(0, 1);
    }
    PH2F(1, 0);
    PH2L(1);

#pragma unroll
    for (int m = 0; m < 4; ++m) {
        int r0r = wm + m * 16 + kg * 4;
#pragma unroll
        for (int j = 0; j < 4; ++j) {
            int gr = row0 + r0r + j;
            if (gr >= n_e) continue;
            int tok = ltok[(size_t)e * Tdim + gr] >> 1;
            float p = lw[(size_t)e * Tdim + gr];
            size_t obase = (size_t)tok * Hdim;
#pragma unroll
            for (int n = 0; n < 4; ++n) {
                int col = col0 + wn + n * 16 + fr;
                float v = p * (acc[m][n][j] + b2[e * Hdim + col]);
                atomicAdd(&out[obase + col], v);
            }
        }
    }
}

// ================= Fallback (round-2 verified) kernels =================
#define FBK 64
#define FLDK 72

__global__ __launch_bounds__(256) void gemm1_fb(
    const float* __restrict__ x, const float* __restrict__ w1,
    const float* __restrict__ b1, const int* __restrict__ cnt,
    const int* __restrict__ ltok, short* __restrict__ hid,
    int CH, int row_base)
{
    int e = blockIdx.z;
    int n_e = cnt[e];
    int row0 = row_base + blockIdx.y * 128;
    if (row0 >= n_e) return;
    int col0 = blockIdx.x * 128;

    __shared__ short As[128][FLDK];
    __shared__ short Bs[128][FLDK];

    int tid = threadIdx.x;
    int arow = tid >> 1;
    int akh  = (tid & 1) * 32;
    int gr_a = row0 + arow;
    int tok = ltok[(size_t)e * Tdim + (gr_a < n_e ? gr_a : n_e - 1)] >> 1;
    const float* xrow = x + (size_t)tok * Hdim + akh;
    int bdg = (tid & 31) * 4;
    int bkg = (tid >> 5) * 4;

    int lane = tid & 63;
    int wid = tid >> 6;
    int wm = (wid >> 1) * 64, wn = (wid & 1) * 64;
    int fr = lane & 15, kg = lane >> 4;

    f32x4 acc[4][4];
#pragma unroll
    for (int m = 0; m < 4; ++m)
#pragma unroll
        for (int n = 0; n < 4; ++n) acc[m][n] = (f32x4)0.0f;

    const float* wB = w1 + (size_t)e * Hdim * Ddim + col0;

    for (int k0 = 0; k0 < Hdim; k0 += FBK) {
#pragma unroll
        for (int i = 0; i < 8; ++i) {
            float4 v = *(const float4*)(xrow + k0 + i * 4);
            s16x4 h; h[0] = f2bf(v.x); h[1] = f2bf(v.y); h[2] = f2bf(v.z); h[3] = f2bf(v.w);
            *(s16x4*)(&As[arow][akh + i * 4]) = h;
        }
#pragma unroll
        for (int r = 0; r < 2; ++r) {
            int kq = bkg + r * 32;
            float4 v0 = *(const float4*)(wB + (size_t)(k0 + kq + 0) * Ddim + bdg);
            float4 v1 = *(const float4*)(wB + (size_t)(k0 + kq + 1) * Ddim + bdg);
            float4 v2 = *(const float4*)(wB + (size_t)(k0 + kq + 2) * Ddim + bdg);
            float4 v3 = *(const float4*)(wB + (size_t)(k0 + kq + 3) * Ddim + bdg);
            const float* p0 = (const float*)&v0; const float* p1 = (const float*)&v1;
            const float* p2 = (const float*)&v2; const float* p3 = (const float*)&v3;
#pragma unroll
            for (int c = 0; c < 4; ++c) {
                s16x4 h; h[0] = f2bf(p0[c]); h[1] = f2bf(p1[c]); h[2] = f2bf(p2[c]); h[3] = f2bf(p3[c]);
                *(s16x4*)(&Bs[bdg + c][kq]) = h;
            }
        }
        __syncthreads();
        bfv8 af[4][2], bfr[4][2];
#pragma unroll
        for (int m = 0; m < 4; ++m)
#pragma unroll
            for (int kk = 0; kk < 2; ++kk)
                af[m][kk] = *(const bfv8*)(&As[wm + m * 16 + fr][kk * 32 + kg * 8]);
#pragma unroll
        for (int n = 0; n < 4; ++n)
#pragma unroll
            for (int kk = 0; kk < 2; ++kk)
                bfr[n][kk] = *(const bfv8*)(&Bs[wn + n * 16 + fr][kk * 32 + kg * 8]);
#pragma unroll
        for (int m = 0; m < 4; ++m)
#pragma unroll
            for (int n = 0; n < 4; ++n) {
                acc[m][n] = __builtin_amdgcn_mfma_f32_16x16x32_bf16(af[m][0], bfr[n][0], acc[m][n], 0, 0, 0);
                acc[m][n] = __builtin_amdgcn_mfma_f32_16x16x32_bf16(af[m][1], bfr[n][1], acc[m][n], 0, 0, 0);
            }
        __syncthreads();
    }

    int lr0 = row0 - row_base;
#pragma unroll
    for (int m = 0; m < 4; ++m) {
        int r0r = wm + m * 16 + kg * 4;
#pragma unroll
        for (int j = 0; j < 4; ++j) {
            int gr = row0 + r0r + j;
            if (gr >= n_e) continue;
            size_t hbase = ((size_t)e * CH + (size_t)(lr0 + r0r + j)) * Ddim;
#pragma unroll
            for (int n = 0; n < 4; ++n) {
                int col = col0 + wn + n * 16 + fr;
                float v = acc[m][n][j] + b1[e * Ddim + col];
                float g = 0.5f * v * (1.0f + erff(v * 0.70710678118654752440f));
                hid[hbase + col] = f2bf(g);
            }
        }
    }
}

__global__ __launch_bounds__(256) void gemm2_fb(
    const short* __restrict__ hid, const float* __restrict__ w2,
    const float* __restrict__ b2, const int* __restrict__ cnt,
    const int* __restrict__ ltok, const float* __restrict__ lw,
    float* __restrict__ out, int CH, int row_base)
{
    int e = blockIdx.z;
    int n_e = cnt[e];
    int row0 = row_base + blockIdx.y * 128;
    if (row0 >= n_e) return;
    int col0 = blockIdx.x * 128;

    __shared__ short As[128][FLDK];
    __shared__ short Bs[128][FLDK];

    int tid = threadIdx.x;
    int arow = tid >> 1;
    int akh  = (tid & 1) * 32;
    const short* hrow = hid + ((size_t)e * CH + (size_t)(row0 - row_base + arow)) * Ddim + akh;
    int bdg = (tid & 31) * 4;
    int bkg = (tid >> 5) * 4;

    int lane = tid & 63;
    int wid = tid >> 6;
    int wm = (wid >> 1) * 64, wn = (wid & 1) * 64;
    int fr = lane & 15, kg = lane >> 4;

    f32x4 acc[4][4];
#pragma unroll
    for (int m = 0; m < 4; ++m)
#pragma unroll
        for (int n = 0; n < 4; ++n) acc[m][n] = (f32x4)0.0f;

    const float* wB = w2 + (size_t)e * Ddim * Hdim + col0;

    for (int k0 = 0; k0 < Ddim; k0 += FBK) {
#pragma unroll
        for (int i = 0; i < 4; ++i) {
            s16x8 v = *(const s16x8*)(hrow + k0 + i * 8);
            *(s16x8*)(&As[arow][akh + i * 8]) = v;
        }
#pragma unroll
        for (int r = 0; r < 2; ++r) {
            int kq = bkg + r * 32;
            float4 v0 = *(const float4*)(wB + (size_t)(k0 + kq + 0) * Hdim + bdg);
            float4 v1 = *(const float4*)(wB + (size_t)(k0 + kq + 1) * Hdim + bdg);
            float4 v2 = *(const float4*)(wB + (size_t)(k0 + kq + 2) * Hdim + bdg);
            float4 v3 = *(const float4*)(wB + (size_t)(k0 + kq + 3) * Hdim + bdg);
            const float* p0 = (const float*)&v0; const float* p1 = (const float*)&v1;
            const float* p2 = (const float*)&v2; const float* p3 = (const float*)&v3;
#pragma unroll
            for (int c = 0; c < 4; ++c) {
                s16x4 h; h[0] = f2bf(p0[c]); h[1] = f2bf(p1[c]); h[2] = f2bf(p2[c]); h[3] = f2bf(p3[c]);
                *(s16x4*)(&Bs[bdg + c][kq]) = h;
            }
        }
        __syncthreads();
        bfv8 af[4][2], bfr[4][2];
#pragma unroll
        for (int m = 0; m < 4; ++m)
#pragma unroll
            for (int kk = 0; kk < 2; ++kk)
                af[m][kk] = *(const bfv8*)(&As[wm + m * 16 + fr][kk * 32 + kg * 8]);
#pragma unroll
        for (int n = 0; n < 4; ++n)
#pragma unroll
            for (int kk = 0; kk < 2; ++kk)
                bfr[n][kk] = *(const bfv8*)(&Bs[wn + n * 16 + fr][kk * 32 + kg * 8]);
#pragma unroll
        for (int m = 0; m < 4; ++m)
#pragma unroll
            for (int n = 0; n < 4; ++n) {
                acc[m][n] = __builtin_amdgcn_mfma_f32_16x16x32_bf16(af[m][0], bfr[n][0], acc[m][n], 0, 0, 0);
                acc[m][n] = __builtin_amdgcn_mfma_f32_16x16x32_bf16(af[m][1], bfr[n][1], acc[m][n], 0, 0, 0);
            }
        __syncthreads();
    }

#pragma unroll
    for (int m = 0; m < 4; ++m) {
        int r0r = wm + m * 16 + kg * 4;
#pragma unroll
        for (int j = 0; j < 4; ++j) {
            int gr = row0 + r0r + j;
            if (gr >= n_e) continue;
            int tok = ltok[(size_t)e * Tdim + gr] >> 1;
            float p = lw[(size_t)e * Tdim + gr];
#pragma unroll
            for (int n = 0; n < 4; ++n) {
                int col = col0 + wn + n * 16 + fr;
                float v = p * (acc[m][n][j] + b2[e * Hdim + col]);
                atomicAdd(&out[(size_t)tok * Hdim + col], v);
            }
        }
    }
}

// ---------------- Host launch ----------------
extern "C" void kernel_launch(void* const* d_in, const int* in_sizes, int n_in,
                              void* d_out, int out_size, void* d_ws, size_t ws_size,
                              hipStream_t stream)
{
    const float* x  = (const float*)d_in[0];
    const float* gw = (const float*)d_in[1];
    const float* w1 = (const float*)d_in[2];
    const float* b1 = (const float*)d_in[3];
    const float* w2 = (const float*)d_in[4];
    const float* b2 = (const float*)d_in[5];
    float* out = (float*)d_out;

    char* wsb = (char*)d_ws;
    // hdr: cnt[8]@0, psum[8]@32, eoff[8]@64, pad to 128
    int*   cnt  = (int*)wsb;
    float* psum = (float*)(wsb + 32);
    int*   eoff = (int*)(wsb + 64);
    int*   ltok = (int*)(wsb + 128);
    float* lwp  = (float*)(wsb + 128 + (size_t)Edim * Tdim * 4);
    size_t lists_end = 128 + (size_t)Edim * Tdim * 8;

    size_t xb_sz = (size_t)Tdim * Hdim * 2;          // 16 MB
    size_t w1t_sz = (size_t)Edim * Hdim * Ddim * 2;  // 32 MB
    size_t w2t_sz = w1t_sz;                          // 32 MB
    size_t hid_sz = (size_t)(2 * Tdim) * Ddim * 2;   // 64 MB (slot-compact)
    size_t req = lists_end + xb_sz + w1t_sz + w2t_sz + hid_sz;

    hipMemsetAsync(wsb, 0, 128, stream);
    hipMemsetAsync(d_out, 0, (size_t)out_size * 4, stream);

    if (req <= ws_size) {
        short* xb   = (short*)(wsb + lists_end);
        short* w1t  = (short*)(wsb + lists_end + xb_sz);
        short* w2t  = (short*)(wsb + lists_end + xb_sz + w1t_sz);
        short* hid  = (short*)(wsb + lists_end + xb_sz + w1t_sz + w2t_sz);

        prep_kernel<<<Tdim / 16 + 8192, 256, 0, stream>>>(
            x, gw, w1, w2, cnt, psum, ltok, lwp, xb, w1t, w2t);
        aux_kernel<<<1, 64, 0, stream>>>(cnt, psum, eoff, out + (size_t)Tdim * Hdim);

        gemm1n_kernel<<<(Ddim / 256) * 32 * Edim, 512, 0, stream>>>(
            xb, w1t, b1, cnt, eoff, ltok, hid);
        gemm2n_kernel<<<(Hdim / 128) * 32 * Edim, 512, 0, stream>>>(
            hid, w2t, b2, cnt, eoff, ltok, lwp, out);
    } else {
        // round-2 verified fallback
        short* hid = (short*)(wsb + lists_end);
        int CH2 = 2048;
        while (CH2 > 128 && lists_end + (size_t)Edim * CH2 * Ddim * 2 > ws_size) CH2 >>= 1;

        router_kernel<<<Tdim / 16, 256, 0, stream>>>(x, gw, cnt, psum, ltok, lwp);
        aux_kernel<<<1, 64, 0, stream>>>(cnt, psum, eoff, out + (size_t)Tdim * Hdim);

        int chunks = Tdim / CH2;
        for (int c = 0; c < chunks; ++c) {
            gemm1_fb<<<dim3(Ddim / 128, CH2 / 128, Edim), 256, 0, stream>>>(
                x, w1, b1, cnt, ltok, hid, CH2, c * CH2);
            gemm2_fb<<<dim3(Hdim / 128, CH2 / 128, Edim), 256, 0, stream>>>(
                hid, w2, b2, cnt, ltok, lwp, out, CH2, c * CH2);
        }
    }
}

// Round 15
// 295.481 us; speedup vs baseline: 1.3271x; 1.3271x over previous
//
#include <hip/hip_runtime.h>
#include <hip/hip_bf16.h>
#include <math.h>

#define Bdim 2
#define Sdim 4096
#define Hdim 1024
#define Edim 8
#define Ddim 2048
#define Tdim (Bdim*Sdim)   // 8192 tokens

typedef __attribute__((ext_vector_type(8))) __bf16 bfv8;
typedef __attribute__((ext_vector_type(8))) short s16x8;
typedef __attribute__((ext_vector_type(4))) short s16x4;
typedef __attribute__((ext_vector_type(4))) float f32x4;

__device__ __forceinline__ short f2bf(float f) {
    union { float f; unsigned u; } a; a.f = f;
    unsigned r = (a.u + 0x7fffu + ((a.u >> 16) & 1u)) >> 16;
    return (short)r;
}
__device__ __forceinline__ float bf2f(short s) {
    union { unsigned u; float f; } a; a.u = ((unsigned)(unsigned short)s) << 16;
    return a.f;
}
// tanh-form gelu via exp; |err| < 1e-3 abs (below bf16 GEMM noise)
__device__ __forceinline__ float fgelu(float x) {
    float u = fminf(x * (1.5957691f + 0.07135481f * x * x), 60.0f);
    float t = __expf(u);
    return x * t / (t + 1.0f);
}

typedef const __attribute__((address_space(1))) unsigned int ga_u32;
typedef __attribute__((address_space(3))) unsigned int la_u32;

__device__ __forceinline__ void gl_lds16(const void* g, void* l) {
    __builtin_amdgcn_global_load_lds((ga_u32*)g, (la_u32*)l, 16, 0, 0);
}

#define SYNC0() do {                                                     \
    asm volatile("s_waitcnt vmcnt(0)" ::: "memory");                     \
    __builtin_amdgcn_s_barrier();                                        \
    __builtin_amdgcn_sched_barrier(0);                                   \
} while (0)

// ---- gemm1 (256x256, af[8] bf[4], 32 MFMA/phase) ----
#define RD1(S) do {                                                                  \
    _Pragma("unroll") for (int n = 0; n < 4; ++n)                                    \
        bf[n] = *(const bfv8*)(lds + 16384 + (S) * 8192 + offB[n]);                  \
    _Pragma("unroll") for (int m = 0; m < 8; ++m)                                    \
        af[m] = *(const bfv8*)(lds + (S) * 8192 + offA[m]);                          \
    __builtin_amdgcn_sched_barrier(0);                                               \
} while (0)
#define MM1() do {                                                                   \
    __builtin_amdgcn_s_setprio(1);                                                   \
    _Pragma("unroll") for (int m = 0; m < 8; ++m)                                    \
        _Pragma("unroll") for (int n = 0; n < 4; ++n)                                \
            acc[m][n] = __builtin_amdgcn_mfma_f32_16x16x32_bf16(af[m], bf[n], acc[m][n], 0, 0, 0); \
    __builtin_amdgcn_s_setprio(0);                                                   \
    __builtin_amdgcn_sched_barrier(0);                                               \
} while (0)
#define PH1F(SST, SRD) do { stage(SST); RD1(SRD); MM1(); SYNC0(); } while (0)
#define PH1L(SRD)      do { RD1(SRD); MM1(); } while (0)

// ---- gemm2 (256x128, af[4] bf[4], 16 MFMA/phase) ----
#define RD2(S) do {                                                                  \
    _Pragma("unroll") for (int n = 0; n < 4; ++n)                                    \
        bf[n] = *(const bfv8*)(lds + 16384 + (S) * 4096 + offB[n]);                  \
    _Pragma("unroll") for (int m = 0; m < 4; ++m)                                    \
        af[m] = *(const bfv8*)(lds + (S) * 8192 + offA[m]);                          \
    __builtin_amdgcn_sched_barrier(0);                                               \
} while (0)
#define MM2() do {                                                                   \
    __builtin_amdgcn_s_setprio(1);                                                   \
    _Pragma("unroll") for (int m = 0; m < 4; ++m)                                    \
        _Pragma("unroll") for (int n = 0; n < 4; ++n)                                \
            acc[m][n] = __builtin_amdgcn_mfma_f32_16x16x32_bf16(af[m], bf[n], acc[m][n], 0, 0, 0); \
    __builtin_amdgcn_s_setprio(0);                                                   \
    __builtin_amdgcn_sched_barrier(0);                                               \
} while (0)
#define PH2F(SST, SRD) do { stage(SST); RD2(SRD); MM2(); SYNC0(); } while (0)
#define PH2L(SRD)      do { RD2(SRD); MM2(); } while (0)

// ---------------- Fused prep: router (blocks 0..511) + weight convert (512..8703) ----------------
union PrepSm {
    struct {
        float gws[Edim * Hdim];
        int lcnt[8], gbase[8];
        int s_e[32], s_pos[32], s_tok[32];
        float s_w[32];
        float s_ps[4][8];
    } r;
    struct { short t[64][76]; } c;
};

__global__ __launch_bounds__(256) void prep_kernel(
    const float* __restrict__ x, const float* __restrict__ gw,
    const float* __restrict__ w1, const float* __restrict__ w2,
    int* __restrict__ cnt, float* __restrict__ psum,
    int* __restrict__ ltok, float* __restrict__ lw,
    short* __restrict__ xb, short* __restrict__ w1t, short* __restrict__ w2t)
{
    __shared__ PrepSm sm;
    int tid = threadIdx.x;

    if (blockIdx.x < Tdim / 16) {
        // ======== router: 512 blocks, wave handles 4 tokens; also emits xb ========
        int bid = blockIdx.x;
        for (int i = tid; i < Edim * Hdim / 4; i += 256)
            ((float4*)sm.r.gws)[i] = ((const float4*)gw)[i];
        if (tid < Edim) sm.r.lcnt[tid] = 0;
        __syncthreads();

        int wave = tid >> 6, lane = tid & 63;
        float ps = 0.f;

        for (int i = 0; i < 4; ++i) {
            int t = bid * 16 + wave * 4 + i;
            double acc[Edim];
#pragma unroll
            for (int e = 0; e < Edim; ++e) acc[e] = 0.0;
#pragma unroll
            for (int kq = 0; kq < 4; ++kq) {
                float4 xv = *(const float4*)(x + (size_t)t * Hdim + kq * 256 + lane * 4);
                s16x4 h; h[0]=f2bf(xv.x); h[1]=f2bf(xv.y); h[2]=f2bf(xv.z); h[3]=f2bf(xv.w);
                *(s16x4*)(xb + (size_t)t * Hdim + kq * 256 + lane * 4) = h;
#pragma unroll
                for (int e = 0; e < Edim; ++e) {
                    float4 wv = *(const float4*)(&sm.r.gws[e * Hdim + kq * 256 + lane * 4]);
                    acc[e] += (double)xv.x * wv.x + (double)xv.y * wv.y
                            + (double)xv.z * wv.z + (double)xv.w * wv.w;
                }
            }
#pragma unroll
            for (int e = 0; e < Edim; ++e) {
                acc[e] += __shfl_xor(acc[e], 1, 64);
                acc[e] += __shfl_xor(acc[e], 2, 64);
                acc[e] += __shfl_xor(acc[e], 4, 64);
            }
            int el = lane & 7;
            double v = acc[0];
#pragma unroll
            for (int e = 1; e < Edim; ++e) if (el == e) v = acc[e];
            v += __shfl_xor(v, 8, 64);
            v += __shfl_xor(v, 16, 64);
            v += __shfl_xor(v, 32, 64);
            double mx = v;
            mx = fmax(mx, __shfl_xor(mx, 1, 64));
            mx = fmax(mx, __shfl_xor(mx, 2, 64));
            mx = fmax(mx, __shfl_xor(mx, 4, 64));
            float ex = __expf((float)(v - mx));
            float smv = ex;
            smv += __shfl_xor(smv, 1, 64);
            smv += __shfl_xor(smv, 2, 64);
            smv += __shfl_xor(smv, 4, 64);
            ps += ex / smv;
            double le[8];
#pragma unroll
            for (int e = 0; e < 8; ++e) le[e] = __shfl(v, e, 8);
            if (lane == 0) {
                int e1 = 0;
#pragma unroll
                for (int e = 1; e < 8; ++e) if (le[e] > le[e1]) e1 = e;
                int e2 = -1;
#pragma unroll
                for (int e = 0; e < 8; ++e) {
                    if (e == e1) continue;
                    if (e2 < 0 || le[e] > le[e2]) e2 = e;
                }
                float r = __expf((float)(le[e2] - le[e1]));   // p2/p1
                float w1v = 1.0f / (1.0f + r);
                int lt = (wave * 4 + i) * 2;
                int p1 = atomicAdd(&sm.r.lcnt[e1], 1);
                sm.r.s_e[lt] = e1; sm.r.s_pos[lt] = p1; sm.r.s_tok[lt] = 2*t;     sm.r.s_w[lt] = w1v;
                int p2 = atomicAdd(&sm.r.lcnt[e2], 1);
                sm.r.s_e[lt+1] = e2; sm.r.s_pos[lt+1] = p2; sm.r.s_tok[lt+1] = 2*t+1; sm.r.s_w[lt+1] = 1.0f - w1v;
            }
        }
        if (lane < 8) sm.r.s_ps[wave][lane] = ps;
        __syncthreads();
        if (tid < 8) {
            atomicAdd(&psum[tid], sm.r.s_ps[0][tid] + sm.r.s_ps[1][tid] + sm.r.s_ps[2][tid] + sm.r.s_ps[3][tid]);
            sm.r.gbase[tid] = atomicAdd(&cnt[tid], sm.r.lcnt[tid]);
        }
        __syncthreads();
        if (tid < 32) {
            int e = sm.r.s_e[tid];
            int pos = sm.r.gbase[e] + sm.r.s_pos[tid];
            ltok[e * Tdim + pos] = sm.r.s_tok[tid];
            lw[e * Tdim + pos] = sm.r.s_w[tid];
        }
    } else {
        // ======== weight transpose-convert: 8192 blocks ========
        int id = blockIdx.x - Tdim / 16;
        int bz = id >> 9, by = (id >> 5) & 15, bx = id & 31;
        const float* w; short* wt; int R, C, r0, c0, e;
        if (bz < 8) { e = bz;     w = w1; wt = w1t; R = Hdim; C = Ddim; r0 = by * 64; c0 = bx * 64; }
        else        { e = bz - 8; w = w2; wt = w2t; R = Ddim; C = Hdim; r0 = bx * 64; c0 = by * 64; }

        {
            int r = tid >> 2, cs = (tid & 3) * 16;
            const float* src = w + ((size_t)e * R + r0 + r) * C + c0 + cs;
#pragma unroll
            for (int q = 0; q < 4; ++q) {
                float4 v = *(const float4*)(src + q * 4);
                s16x4 h; h[0]=f2bf(v.x); h[1]=f2bf(v.y); h[2]=f2bf(v.z); h[3]=f2bf(v.w);
                *(s16x4*)(&sm.c.t[r][cs + q * 4]) = h;
            }
        }
        __syncthreads();
        {
            int c = tid >> 2, rs = (tid & 3) * 16;
            short tmp[16];
#pragma unroll
            for (int j = 0; j < 16; ++j) tmp[j] = sm.c.t[rs + j][c];
            short* dst = wt + ((size_t)e * C + c0 + c) * R + r0 + rs;
            *(s16x8*)dst = *(s16x8*)tmp;
            *(s16x8*)(dst + 8) = *(s16x8*)(tmp + 8);
        }
    }
}

// ---------------- Aux loss + prefix offsets ----------------
__global__ void aux_kernel(const int* __restrict__ cnt,
                           const float* __restrict__ psum,
                           int* __restrict__ eoff,
                           float* __restrict__ out_aux)
{
    if (threadIdx.x == 0 && blockIdx.x == 0) {
        double s = 0.0;
        int run = 0;
        for (int e = 0; e < Edim; ++e) {
            eoff[e] = run;
            run += cnt[e];
            s += ((double)cnt[e] / (double)Bdim) * ((double)psum[e] / (double)Tdim);
        }
        out_aux[0] = (float)((double)Edim * s);
    }
}

// ---------------- Router (fallback path only) ----------------
__global__ __launch_bounds__(256) void router_kernel(
    const float* __restrict__ x, const float* __restrict__ gw,
    int* __restrict__ cnt, float* __restrict__ psum,
    int* __restrict__ ltok, float* __restrict__ lw)
{
    __shared__ float gws[Edim * Hdim];
    __shared__ int   lcnt[Edim], gbase[Edim];
    __shared__ int   s_e[32], s_pos[32], s_tok[32];
    __shared__ float s_w[32];
    __shared__ float s_ps[4][8];

    int tid = threadIdx.x;
    for (int i = tid; i < Edim * Hdim / 4; i += 256)
        ((float4*)gws)[i] = ((const float4*)gw)[i];
    if (tid < Edim) lcnt[tid] = 0;
    __syncthreads();

    int wave = tid >> 6, lane = tid & 63;
    float ps = 0.f;

    for (int i = 0; i < 4; ++i) {
        int t = blockIdx.x * 16 + wave * 4 + i;
        double acc[Edim];
#pragma unroll
        for (int e = 0; e < Edim; ++e) acc[e] = 0.0;
#pragma unroll
        for (int kq = 0; kq < 4; ++kq) {
            float4 xv = *(const float4*)(x + (size_t)t * Hdim + kq * 256 + lane * 4);
#pragma unroll
            for (int e = 0; e < Edim; ++e) {
                float4 wv = *(const float4*)(&gws[e * Hdim + kq * 256 + lane * 4]);
                acc[e] += (double)xv.x * wv.x + (double)xv.y * wv.y
                        + (double)xv.z * wv.z + (double)xv.w * wv.w;
            }
        }
#pragma unroll
        for (int e = 0; e < Edim; ++e) {
            acc[e] += __shfl_xor(acc[e], 1, 64);
            acc[e] += __shfl_xor(acc[e], 2, 64);
            acc[e] += __shfl_xor(acc[e], 4, 64);
        }
        int el = lane & 7;
        double v = acc[0];
#pragma unroll
        for (int e = 1; e < Edim; ++e) if (el == e) v = acc[e];
        v += __shfl_xor(v, 8, 64);
        v += __shfl_xor(v, 16, 64);
        v += __shfl_xor(v, 32, 64);
        double mx = v;
        mx = fmax(mx, __shfl_xor(mx, 1, 64));
        mx = fmax(mx, __shfl_xor(mx, 2, 64));
        mx = fmax(mx, __shfl_xor(mx, 4, 64));
        float ex = __expf((float)(v - mx));
        float smv = ex;
        smv += __shfl_xor(smv, 1, 64);
        smv += __shfl_xor(smv, 2, 64);
        smv += __shfl_xor(smv, 4, 64);
        ps += ex / smv;
        double le[8];
#pragma unroll
        for (int e = 0; e < 8; ++e) le[e] = __shfl(v, e, 8);
        if (lane == 0) {
            int e1 = 0;
#pragma unroll
            for (int e = 1; e < 8; ++e) if (le[e] > le[e1]) e1 = e;
            int e2 = -1;
#pragma unroll
            for (int e = 0; e < 8; ++e) {
                if (e == e1) continue;
                if (e2 < 0 || le[e] > le[e2]) e2 = e;
            }
            float r = __expf((float)(le[e2] - le[e1]));
            float w1v = 1.0f / (1.0f + r);
            int lt = (wave * 4 + i) * 2;
            int p1 = atomicAdd(&lcnt[e1], 1);
            s_e[lt] = e1; s_pos[lt] = p1; s_tok[lt] = 2*t;     s_w[lt] = w1v;
            int p2 = atomicAdd(&lcnt[e2], 1);
            s_e[lt+1] = e2; s_pos[lt+1] = p2; s_tok[lt+1] = 2*t+1; s_w[lt+1] = 1.0f - w1v;
        }
    }
    if (lane < 8) s_ps[wave][lane] = ps;
    __syncthreads();
    if (tid < 8) {
        atomicAdd(&psum[tid], s_ps[0][tid] + s_ps[1][tid] + s_ps[2][tid] + s_ps[3][tid]);
        gbase[tid] = atomicAdd(&cnt[tid], lcnt[tid]);
    }
    __syncthreads();
    if (tid < 32) {
        int e = s_e[tid];
        int pos = gbase[e] + s_pos[tid];
        ltok[e * Tdim + pos] = s_tok[tid];
        lw[e * Tdim + pos] = s_w[tid];
    }
}

// ====== GEMM1: 256x256, 8 waves (wave-tile 128x64), BK=32, 2 slots, 64KB LDS ======
__global__ __launch_bounds__(512, 2) void gemm1n_kernel(
    const short* __restrict__ xb, const short* __restrict__ w1t,
    const float* __restrict__ b1, const int* __restrict__ cnt,
    const int* __restrict__ eoff, const int* __restrict__ ltok,
    short* __restrict__ hid)
{
    constexpr int GXN = Ddim / 256;  // 8
    int id = blockIdx.x;
    int e = id & 7;                  // expert == XCD
    unsigned rem = (unsigned)id >> 3;
    int bx = rem & (GXN - 1);
    int by = rem / GXN;

    int n_e = cnt[e];
    int row0 = by * 256;
    if (row0 >= n_e) return;
    int col0 = bx * 256;
    int slot0 = eoff[e];

    __shared__ short lds[32768];     // 64 KB
    char* ldsb = (char*)lds;

    int tid = threadIdx.x;
    int w = tid >> 6, lane = tid & 63;

    const short* aS[2]; const short* bS[2];
    int oD[2];
#pragma unroll
    for (int j = 0; j < 2; ++j) {
        int o = tid * 16 + j * 8192;               // dest byte offset within 16KB region
        oD[j] = o;
        int eff = o ^ (((o >> 7) & 7) << 4);       // inverse swizzle
        int row = ((eff >> 7) << 1) | ((eff >> 6) & 1);
        int kB  = eff & 63;
        int gr = row0 + row; if (gr > n_e - 1) gr = n_e - 1;
        int tok = ltok[(size_t)e * Tdim + gr] >> 1;
        aS[j] = xb + (size_t)tok * Hdim + (kB >> 1);
        bS[j] = w1t + ((size_t)e * Ddim + col0 + row) * Hdim + (kB >> 1);
    }

    int fr = lane & 15, kg = lane >> 4;
    int wm = (w >> 2) * 128, wn = (w & 3) * 64;

    int offA[8], offB[4];
#pragma unroll
    for (int m = 0; m < 8; ++m) {
        int r = wm + m * 16 + fr;
        offA[m] = (r >> 1) * 64 + ((((r & 1) * 32) + kg * 8) ^ (((r >> 1) & 7) << 3));
    }
#pragma unroll
    for (int n = 0; n < 4; ++n) {
        int r = wn + n * 16 + fr;
        offB[n] = (r >> 1) * 64 + ((((r & 1) * 32) + kg * 8) ^ (((r >> 1) & 7) << 3));
    }

    f32x4 acc[8][4];
#pragma unroll
    for (int m = 0; m < 8; ++m)
#pragma unroll
        for (int n = 0; n < 4; ++n) acc[m][n] = (f32x4)0.0f;

    bfv8 af[8], bf[4];

    auto stage = [&](int s) {    // 4 gl_lds; advances K by 32 shorts
#pragma unroll
        for (int j = 0; j < 2; ++j) {
            gl_lds16(aS[j], ldsb + s * 16384 + oD[j]);
            aS[j] += 32;
            gl_lds16(bS[j], ldsb + 32768 + s * 16384 + oD[j]);
            bS[j] += 32;
        }
    };

    constexpr int NH = Hdim / 32;    // 32 phases
    stage(0);
    SYNC0();
#pragma unroll 1
    for (int it = 0; it < (NH - 2) / 2; ++it) {
        PH1F(1, 0);
        PH1F(0, 1);
    }
    PH1F(1, 0);
    PH1L(1);

#pragma unroll
    for (int m = 0; m < 8; ++m) {
        int r0r = wm + m * 16 + kg * 4;
#pragma unroll
        for (int j = 0; j < 4; ++j) {
            int gr = row0 + r0r + j;
            if (gr >= n_e) continue;
            size_t hbase = (size_t)(slot0 + gr) * Ddim;
#pragma unroll
            for (int n = 0; n < 4; ++n) {
                int col = col0 + wn + n * 16 + fr;
                float v = acc[m][n][j] + b1[e * Ddim + col];
                hid[hbase + col] = f2bf(fgelu(v));
            }
        }
    }
}

// ====== GEMM2: 256x128, 8 waves (wave-tile 64x64), BK=32, 2 slots, 48KB LDS ======
// epilogue: bf16 stores to out2[2t+k] rows (combine kernel sums the 2 slots)
__global__ __launch_bounds__(512, 2) void gemm2n_kernel(
    const short* __restrict__ hid, const short* __restrict__ w2t,
    const float* __restrict__ b2, const int* __restrict__ cnt,
    const int* __restrict__ eoff, const int* __restrict__ ltok,
    const float* __restrict__ lw, short* __restrict__ out2)
{
    constexpr int GXN = Hdim / 128;  // 8
    int id = blockIdx.x;
    int e = id & 7;
    unsigned rem = (unsigned)id >> 3;
    int bx = rem & (GXN - 1);
    int by = rem / GXN;

    int n_e = cnt[e];
    int row0 = by * 256;
    if (row0 >= n_e) return;
    int col0 = bx * 128;
    int slot0 = eoff[e];

    __shared__ short lds[24576];     // 48 KB: A 2x16KB, B 2x8KB
    char* ldsb = (char*)lds;

    int tid = threadIdx.x;
    int w = tid >> 6, lane = tid & 63;

    const short* aS[2]; const short* bS0;
    int oD[2], oB;
#pragma unroll
    for (int j = 0; j < 2; ++j) {
        int o = tid * 16 + j * 8192;
        oD[j] = o;
        int eff = o ^ (((o >> 7) & 7) << 4);
        int row = ((eff >> 7) << 1) | ((eff >> 6) & 1);
        int kB  = eff & 63;
        int gr = row0 + row; if (gr > n_e - 1) gr = n_e - 1;
        aS[j] = hid + (size_t)(slot0 + gr) * Ddim + (kB >> 1);
    }
    {
        int o = tid * 16;
        oB = o;
        int eff = o ^ (((o >> 7) & 7) << 4);
        int row = ((eff >> 7) << 1) | ((eff >> 6) & 1);   // 0..127
        int kB  = eff & 63;
        bS0 = w2t + ((size_t)e * Hdim + col0 + row) * Ddim + (kB >> 1);
    }

    int fr = lane & 15, kg = lane >> 4;
    int wm = (w >> 1) * 64, wn = (w & 1) * 64;

    int offA[4], offB[4];
#pragma unroll
    for (int m = 0; m < 4; ++m) {
        int r = wm + m * 16 + fr;
        offA[m] = (r >> 1) * 64 + ((((r & 1) * 32) + kg * 8) ^ (((r >> 1) & 7) << 3));
    }
#pragma unroll
    for (int n = 0; n < 4; ++n) {
        int r = wn + n * 16 + fr;
        offB[n] = (r >> 1) * 64 + ((((r & 1) * 32) + kg * 8) ^ (((r >> 1) & 7) << 3));
    }

    f32x4 acc[4][4];
#pragma unroll
    for (int m = 0; m < 4; ++m)
#pragma unroll
        for (int n = 0; n < 4; ++n) acc[m][n] = (f32x4)0.0f;

    bfv8 af[4], bf[4];

    auto stage = [&](int s) {    // 3 gl_lds; advances K by 32 shorts
#pragma unroll
        for (int j = 0; j < 2; ++j) {
            gl_lds16(aS[j], ldsb + s * 16384 + oD[j]);
            aS[j] += 32;
        }
        gl_lds16(bS0, ldsb + 32768 + s * 8192 + oB);
        bS0 += 32;
    };

    constexpr int NH = Ddim / 32;    // 64 phases
    stage(0);
    SYNC0();
#pragma unroll 1
    for (int it = 0; it < (NH - 2) / 2; ++it) {
        PH2F(1, 0);
        PH2F(0, 1);
    }
    PH2F(1, 0);
    PH2L(1);

#pragma unroll
    for (int m = 0; m < 4; ++m) {
        int r0r = wm + m * 16 + kg * 4;
#pragma unroll
        for (int j = 0; j < 4; ++j) {
            int gr = row0 + r0r + j;
            if (gr >= n_e) continue;
            int val = ltok[(size_t)e * Tdim + gr];
            float p = lw[(size_t)e * Tdim + gr];
            size_t obase = (size_t)val * Hdim;
#pragma unroll
            for (int n = 0; n < 4; ++n) {
                int col = col0 + wn + n * 16 + fr;
                float v = p * (acc[m][n][j] + b2[e * Hdim + col]);
                out2[obase + col] = f2bf(v);
            }
        }
    }
}

// ---------------- Combine: out[t] = out2[2t] + out2[2t+1] ----------------
__global__ __launch_bounds__(256) void combine_kernel(const short* __restrict__ out2,
                                                      float* __restrict__ out)
{
    size_t i = ((size_t)blockIdx.x * 256 + threadIdx.x) * 8;
    size_t t = i >> 10;
    int h = (int)(i & 1023);
    s16x8 a = *(const s16x8*)(out2 + (t * 2) * 1024 + h);
    s16x8 b = *(const s16x8*)(out2 + (t * 2 + 1) * 1024 + h);
    float4 o0, o1;
    o0.x = bf2f(a[0]) + bf2f(b[0]); o0.y = bf2f(a[1]) + bf2f(b[1]);
    o0.z = bf2f(a[2]) + bf2f(b[2]); o0.w = bf2f(a[3]) + bf2f(b[3]);
    o1.x = bf2f(a[4]) + bf2f(b[4]); o1.y = bf2f(a[5]) + bf2f(b[5]);
    o1.z = bf2f(a[6]) + bf2f(b[6]); o1.w = bf2f(a[7]) + bf2f(b[7]);
    *(float4*)(out + i) = o0;
    *(float4*)(out + i + 4) = o1;
}

// ================= Fallback (round-2 verified) kernels =================
#define FBK 64
#define FLDK 72

__global__ __launch_bounds__(256) void gemm1_fb(
    const float* __restrict__ x, const float* __restrict__ w1,
    const float* __restrict__ b1, const int* __restrict__ cnt,
    const int* __restrict__ ltok, short* __restrict__ hid,
    int CH, int row_base)
{
    int e = blockIdx.z;
    int n_e = cnt[e];
    int row0 = row_base + blockIdx.y * 128;
    if (row0 >= n_e) return;
    int col0 = blockIdx.x * 128;

    __shared__ short As[128][FLDK];
    __shared__ short Bs[128][FLDK];

    int tid = threadIdx.x;
    int arow = tid >> 1;
    int akh  = (tid & 1) * 32;
    int gr_a = row0 + arow;
    int tok = ltok[(size_t)e * Tdim + (gr_a < n_e ? gr_a : n_e - 1)] >> 1;
    const float* xrow = x + (size_t)tok * Hdim + akh;
    int bdg = (tid & 31) * 4;
    int bkg = (tid >> 5) * 4;

    int lane = tid & 63;
    int wid = tid >> 6;
    int wm = (wid >> 1) * 64, wn = (wid & 1) * 64;
    int fr = lane & 15, kg = lane >> 4;

    f32x4 acc[4][4];
#pragma unroll
    for (int m = 0; m < 4; ++m)
#pragma unroll
        for (int n = 0; n < 4; ++n) acc[m][n] = (f32x4)0.0f;

    const float* wB = w1 + (size_t)e * Hdim * Ddim + col0;

    for (int k0 = 0; k0 < Hdim; k0 += FBK) {
#pragma unroll
        for (int i = 0; i < 8; ++i) {
            float4 v = *(const float4*)(xrow + k0 + i * 4);
            s16x4 h; h[0] = f2bf(v.x); h[1] = f2bf(v.y); h[2] = f2bf(v.z); h[3] = f2bf(v.w);
            *(s16x4*)(&As[arow][akh + i * 4]) = h;
        }
#pragma unroll
        for (int r = 0; r < 2; ++r) {
            int kq = bkg + r * 32;
            float4 v0 = *(const float4*)(wB + (size_t)(k0 + kq + 0) * Ddim + bdg);
            float4 v1 = *(const float4*)(wB + (size_t)(k0 + kq + 1) * Ddim + bdg);
            float4 v2 = *(const float4*)(wB + (size_t)(k0 + kq + 2) * Ddim + bdg);
            float4 v3 = *(const float4*)(wB + (size_t)(k0 + kq + 3) * Ddim + bdg);
            const float* p0 = (const float*)&v0; const float* p1 = (const float*)&v1;
            const float* p2 = (const float*)&v2; const float* p3 = (const float*)&v3;
#pragma unroll
            for (int c = 0; c < 4; ++c) {
                s16x4 h; h[0] = f2bf(p0[c]); h[1] = f2bf(p1[c]); h[2] = f2bf(p2[c]); h[3] = f2bf(p3[c]);
                *(s16x4*)(&Bs[bdg + c][kq]) = h;
            }
        }
        __syncthreads();
        bfv8 af[4][2], bfr[4][2];
#pragma unroll
        for (int m = 0; m < 4; ++m)
#pragma unroll
            for (int kk = 0; kk < 2; ++kk)
                af[m][kk] = *(const bfv8*)(&As[wm + m * 16 + fr][kk * 32 + kg * 8]);
#pragma unroll
        for (int n = 0; n < 4; ++n)
#pragma unroll
            for (int kk = 0; kk < 2; ++kk)
                bfr[n][kk] = *(const bfv8*)(&Bs[wn + n * 16 + fr][kk * 32 + kg * 8]);
#pragma unroll
        for (int m = 0; m < 4; ++m)
#pragma unroll
            for (int n = 0; n < 4; ++n) {
                acc[m][n] = __builtin_amdgcn_mfma_f32_16x16x32_bf16(af[m][0], bfr[n][0], acc[m][n], 0, 0, 0);
                acc[m][n] = __builtin_amdgcn_mfma_f32_16x16x32_bf16(af[m][1], bfr[n][1], acc[m][n], 0, 0, 0);
            }
        __syncthreads();
    }

    int lr0 = row0 - row_base;
#pragma unroll
    for (int m = 0; m < 4; ++m) {
        int r0r = wm + m * 16 + kg * 4;
#pragma unroll
        for (int j = 0; j < 4; ++j) {
            int gr = row0 + r0r + j;
            if (gr >= n_e) continue;
            size_t hbase = ((size_t)e * CH + (size_t)(lr0 + r0r + j)) * Ddim;
#pragma unroll
            for (int n = 0; n < 4; ++n) {
                int col = col0 + wn + n * 16 + fr;
                float v = acc[m][n][j] + b1[e * Ddim + col];
                float g = 0.5f * v * (1.0f + erff(v * 0.70710678118654752440f));
                hid[hbase + col] = f2bf(g);
            }
        }
    }
}

__global__ __launch_bounds__(256) void gemm2_fb(
    const short* __restrict__ hid, const float* __restrict__ w2,
    const float* __restrict__ b2, const int* __restrict__ cnt,
    const int* __restrict__ ltok, const float* __restrict__ lw,
    float* __restrict__ out, int CH, int row_base)
{
    int e = blockIdx.z;
    int n_e = cnt[e];
    int row0 = row_base + blockIdx.y * 128;
    if (row0 >= n_e) return;
    int col0 = blockIdx.x * 128;

    __shared__ short As[128][FLDK];
    __shared__ short Bs[128][FLDK];

    int tid = threadIdx.x;
    int arow = tid >> 1;
    int akh  = (tid & 1) * 32;
    const short* hrow = hid + ((size_t)e * CH + (size_t)(row0 - row_base + arow)) * Ddim + akh;
    int bdg = (tid & 31) * 4;
    int bkg = (tid >> 5) * 4;

    int lane = tid & 63;
    int wid = tid >> 6;
    int wm = (wid >> 1) * 64, wn = (wid & 1) * 64;
    int fr = lane & 15, kg = lane >> 4;

    f32x4 acc[4][4];
#pragma unroll
    for (int m = 0; m < 4; ++m)
#pragma unroll
        for (int n = 0; n < 4; ++n) acc[m][n] = (f32x4)0.0f;

    const float* wB = w2 + (size_t)e * Ddim * Hdim + col0;

    for (int k0 = 0; k0 < Ddim; k0 += FBK) {
#pragma unroll
        for (int i = 0; i < 4; ++i) {
            s16x8 v = *(const s16x8*)(hrow + k0 + i * 8);
            *(s16x8*)(&As[arow][akh + i * 8]) = v;
        }
#pragma unroll
        for (int r = 0; r < 2; ++r) {
            int kq = bkg + r * 32;
            float4 v0 = *(const float4*)(wB + (size_t)(k0 + kq + 0) * Hdim + bdg);
            float4 v1 = *(const float4*)(wB + (size_t)(k0 + kq + 1) * Hdim + bdg);
            float4 v2 = *(const float4*)(wB + (size_t)(k0 + kq + 2) * Hdim + bdg);
            float4 v3 = *(const float4*)(wB + (size_t)(k0 + kq + 3) * Hdim + bdg);
            const float* p0 = (const float*)&v0; const float* p1 = (const float*)&v1;
            const float* p2 = (const float*)&v2; const float* p3 = (const float*)&v3;
#pragma unroll
            for (int c = 0; c < 4; ++c) {
                s16x4 h; h[0] = f2bf(p0[c]); h[1] = f2bf(p1[c]); h[2] = f2bf(p2[c]); h[3] = f2bf(p3[c]);
                *(s16x4*)(&Bs[bdg + c][kq]) = h;
            }
        }
        __syncthreads();
        bfv8 af[4][2], bfr[4][2];
#pragma unroll
        for (int m = 0; m < 4; ++m)
#pragma unroll
            for (int kk = 0; kk < 2; ++kk)
                af[m][kk] = *(const bfv8*)(&As[wm + m * 16 + fr][kk * 32 + kg * 8]);
#pragma unroll
        for (int n = 0; n < 4; ++n)
#pragma unroll
            for (int kk = 0; kk < 2; ++kk)
                bfr[n][kk] = *(const bfv8*)(&Bs[wn + n * 16 + fr][kk * 32 + kg * 8]);
#pragma unroll
        for (int m = 0; m < 4; ++m)
#pragma unroll
            for (int n = 0; n < 4; ++n) {
                acc[m][n] = __builtin_amdgcn_mfma_f32_16x16x32_bf16(af[m][0], bfr[n][0], acc[m][n], 0, 0, 0);
                acc[m][n] = __builtin_amdgcn_mfma_f32_16x16x32_bf16(af[m][1], bfr[n][1], acc[m][n], 0, 0, 0);
            }
        __syncthreads();
    }

#pragma unroll
    for (int m = 0; m < 4; ++m) {
        int r0r = wm + m * 16 + kg * 4;
#pragma unroll
        for (int j = 0; j < 4; ++j) {
            int gr = row0 + r0r + j;
            if (gr >= n_e) continue;
            int tok = ltok[(size_t)e * Tdim + gr] >> 1;
            float p = lw[(size_t)e * Tdim + gr];
#pragma unroll
            for (int n = 0; n < 4; ++n) {
                int col = col0 + wn + n * 16 + fr;
                float v = p * (acc[m][n][j] + b2[e * Hdim + col]);
                atomicAdd(&out[(size_t)tok * Hdim + col], v);
            }
        }
    }
}

// ---------------- Host launch ----------------
extern "C" void kernel_launch(void* const* d_in, const int* in_sizes, int n_in,
                              void* d_out, int out_size, void* d_ws, size_t ws_size,
                              hipStream_t stream)
{
    const float* x  = (const float*)d_in[0];
    const float* gw = (const float*)d_in[1];
    const float* w1 = (const float*)d_in[2];
    const float* b1 = (const float*)d_in[3];
    const float* w2 = (const float*)d_in[4];
    const float* b2 = (const float*)d_in[5];
    float* out = (float*)d_out;

    char* wsb = (char*)d_ws;
    // hdr: cnt[8]@0, psum[8]@32, eoff[8]@64, pad to 128
    int*   cnt  = (int*)wsb;
    float* psum = (float*)(wsb + 32);
    int*   eoff = (int*)(wsb + 64);
    int*   ltok = (int*)(wsb + 128);
    float* lwp  = (float*)(wsb + 128 + (size_t)Edim * Tdim * 4);
    size_t lists_end = 128 + (size_t)Edim * Tdim * 8;

    size_t xb_sz = (size_t)Tdim * Hdim * 2;          // 16 MB
    size_t w1t_sz = (size_t)Edim * Hdim * Ddim * 2;  // 32 MB
    size_t w2t_sz = w1t_sz;                          // 32 MB
    size_t hid_sz = (size_t)(2 * Tdim) * Ddim * 2;   // 64 MB (slot-compact)
    size_t req = lists_end + xb_sz + w1t_sz + w2t_sz + hid_sz;

    hipMemsetAsync(wsb, 0, 128, stream);

    if (req <= ws_size) {
        short* xb   = (short*)(wsb + lists_end);
        short* w1t  = (short*)(wsb + lists_end + xb_sz);
        short* w2t  = (short*)(wsb + lists_end + xb_sz + w1t_sz);
        short* hid  = (short*)(wsb + lists_end + xb_sz + w1t_sz + w2t_sz);
        short* out2 = w1t;   // alias: w1t dead once all gemm1n blocks finish

        prep_kernel<<<Tdim / 16 + 8192, 256, 0, stream>>>(
            x, gw, w1, w2, cnt, psum, ltok, lwp, xb, w1t, w2t);
        aux_kernel<<<1, 64, 0, stream>>>(cnt, psum, eoff, out + (size_t)Tdim * Hdim);

        gemm1n_kernel<<<(Ddim / 256) * 32 * Edim, 512, 0, stream>>>(
            xb, w1t, b1, cnt, eoff, ltok, hid);
        gemm2n_kernel<<<(Hdim / 128) * 32 * Edim, 512, 0, stream>>>(
            hid, w2t, b2, cnt, eoff, ltok, lwp, out2);
        combine_kernel<<<(size_t)Tdim * Hdim / 2048, 256, 0, stream>>>(out2, out);
    } else {
        // round-2 verified fallback
        short* hid = (short*)(wsb + lists_end);
        int CH2 = 2048;
        while (CH2 > 128 && lists_end + (size_t)Edim * CH2 * Ddim * 2 > ws_size) CH2 >>= 1;

        hipMemsetAsync(d_out, 0, (size_t)out_size * 4, stream);
        router_kernel<<<Tdim / 16, 256, 0, stream>>>(x, gw, cnt, psum, ltok, lwp);
        aux_kernel<<<1, 64, 0, stream>>>(cnt, psum, eoff, out + (size_t)Tdim * Hdim);

        int chunks = Tdim / CH2;
        for (int c = 0; c < chunks; ++c) {
            gemm1_fb<<<dim3(Ddim / 128, CH2 / 128, Edim), 256, 0, stream>>>(
                x, w1, b1, cnt, ltok, hid, CH2, c * CH2);
            gemm2_fb<<<dim3(Hdim / 128, CH2 / 128, Edim), 256, 0, stream>>>(
                hid, w2, b2, cnt, ltok, lwp, out, CH2, c * CH2);
        }
    }
}